// Round 25
// baseline (105.152 us; speedup 1.0000x reference)
//
#include <hip/hip_runtime.h>
#include <hip/hip_bf16.h>

// Sheaf CNN on the fixed ring graph (offsets ±1..4 mod 4096, degree 8).
// SINGLE fused dispatch (grid 256 x 1024), LDS-overlay design:
//   phase A: weights packed in LDS (Wa|Wb bf16-pair u32, Wh/W2 u16) + ef ext
//            rows; GEMV 32 ext nodes (2/wave), pure-LDS inner loop.
//   phase B: As/Bs/Gs overlay the dead P1 region; proven phases 2-4.
//   finalize: last-block (threadfence + atomic counter, R21-proven);
//            Wc1/Wc2 overlay; fixed-order reduce + classifier -> d_out.
// f32-probe path: R21-style global-load fused body (never triggers).
// Fallbacks byte-preserved: ws>=32KB -> R17 128-block halo kernel +
// finalize; else R8 single-block.

#define NN    4096
#define CHK   32            // R17 fallback: chunk nodes
#define EXT   48            // R17 fallback: chunk + 2*8 halo
#define PEXT  40            // R17 fallback: chunk + 2*4 halo
#define NGRID 128           // R17 fallback grid
#define WS_R17 (NGRID * 64u * 4u)

#define NBLKF 256           // fused grid (16 owned nodes/block)
#define WS_FUSED (4096u + NBLKF * 64u * 4u)

struct Smem {
    float As[EXT][64];
    float Bs[EXT][64];
    float Gs[EXT][64];
    float Hs[16][64];
    float ps[PEXT][8][2];
    float dinvs[PEXT][2];
    float facs[PEXT][2];
    float red[1024];
    float pooled[64];
    float hid[128];
};

struct SmemFin {
    float Wc1s[64][128];
    float Wc2s[128][8];
    float red[256];
    float pooled[64];
    float hid[128];
};

template <bool F32>
static __device__ __forceinline__ float ldv(const void* p, int i) {
    if constexpr (F32) return ((const float*)p)[i];
    else return __bfloat162float(((const __hip_bfloat16*)p)[i]);
}

static __device__ __forceinline__ float ldr(const void* p, int i, bool f32) {
    if (f32) return ((const float*)p)[i];
    return __bfloat162float(((const __hip_bfloat16*)p)[i]);
}

static __device__ __forceinline__ float blo(unsigned u) {
    return __uint_as_float(u << 16);
}
static __device__ __forceinline__ float bhi(unsigned u) {
    return __uint_as_float(u & 0xFFFF0000u);
}
static __device__ __forceinline__ float b16f(unsigned short u) {
    return __uint_as_float(((unsigned)u) << 16);
}

// ---------- R8/R17-proven halo body (fallback paths) ----------
template <bool F32>
static __device__ void body(Smem& sm,
    const void* ef, const void* We, const void* be, const void* M1w,
    const void* M1b, const void* M2w, const void* M2b, const void* W1,
    const void* W2, const void* Wc1, const void* bc1, const void* Wc2,
    const void* bc2, void* out)
{
    const int t = threadIdx.x;
    const int c = t & 63;
    const int w = t >> 6;
    const int a = (t >> 6) & 1;
    const int ms = t >> 7;

    const float m1b_c = ldv<F32>(M1b, c);
    const float m2w0  = ldv<F32>(M2w, c * 2 + 0);
    const float m2w1  = ldv<F32>(M2w, c * 2 + 1);
    const float m2b0  = ldv<F32>(M2b, 0);
    const float m2b1  = ldv<F32>(M2b, 1);
    const float cs0 = ldv<F32>(W1, 0) + ldv<F32>(W1, 2);
    const float cs1 = ldv<F32>(W1, 1) + ldv<F32>(W1, 3);
    const float bec = ldv<F32>(be, c);

    float accY = 0.f;

    for (int ch = blockIdx.x; ch < NN / CHK; ch += gridDim.x) {
        const int c0 = ch * CHK;
        for (int pp = 0; pp < EXT / 16; ++pp) {
            const int q  = pp * 16 + w;
            const int gi = (c0 - 8 + q) & (NN - 1);
            float aA = 0.f, aB = 0.f, aH = bec;
            #pragma unroll 2
            for (int k = 0; k < 128; ++k) {
                const float ev = ldv<F32>(ef, gi * 128 + k);
                aA += ev * ldv<F32>(M1w, k * 64 + c);
                aB += ev * ldv<F32>(M1w, 8192 + k * 64 + c);
                aH += ev * ldv<F32>(We, k * 64 + c);
            }
            sm.As[q][c] = aA;
            sm.Bs[q][c] = aB;
            sm.Hs[w][c] = fmaxf(aH, 0.f);
            __syncthreads();
            float aG = 0.f;
            #pragma unroll 2
            for (int k = 0; k < 64; ++k)
                aG += sm.Hs[w][k] * ldv<F32>(W2, k * 64 + c);
            sm.Gs[q][c] = aG;
            __syncthreads();
        }
        for (int pi = w; pi < PEXT * 8; pi += 16) {
            const int r  = pi >> 3;
            const int tt = pi & 7;
            const int off = (tt < 4) ? (tt - 4) : (tt - 3);
            const float h = fmaxf(sm.As[r + 4][c] + sm.Bs[r + 4 + off][c] + m1b_c, 0.f);
            float q0 = h * m2w0, q1 = h * m2w1;
            #pragma unroll
            for (int d2 = 32; d2; d2 >>= 1) {
                q0 += __shfl_xor(q0, d2);
                q1 += __shfl_xor(q1, d2);
            }
            if (c == 0) {
                sm.ps[r][tt][0] = q0 + m2b0;
                sm.ps[r][tt][1] = q1 + m2b1;
            }
        }
        __syncthreads();
        if (t < PEXT * 2) {
            const int r = t >> 1, aa = t & 1;
            float s = 0.f;
            #pragma unroll
            for (int tt = 0; tt < 8; ++tt) { const float p = sm.ps[r][tt][aa]; s += p * p; }
            const float dv = 1.f / sqrtf(fmaxf(s + 1e-5f, 1e-6f));
            sm.dinvs[r][aa] = dv;
            sm.facs[r][aa]  = 1.f - dv * dv * s;
        }
        __syncthreads();
        const float csa = a ? cs1 : cs0;
        #pragma unroll
        for (int it = 0; it < 4; ++it) {
            const int m = it * 8 + ms;
            const int r = m + 4;
            const int g = m + 8;
            const float di = sm.dinvs[r][a];
            float v = sm.facs[r][a] * sm.Gs[g][c];
            #pragma unroll
            for (int tt = 0; tt < 8; ++tt) {
                const int off = (tt < 4) ? (tt - 4) : (tt - 3);
                v += di * sm.ps[r + off][7 - tt][a] * sm.ps[r][tt][a]
                        * sm.dinvs[r + off][a] * sm.Gs[g + off][c];
            }
            const float x = csa * v;
            accY += (x > 0.f) ? x : expm1f(x);
        }
        __syncthreads();
    }

    sm.red[t] = accY;
    __syncthreads();

    if (gridDim.x > 1) {
        if (t < 64) {
            float s = 0.f;
            #pragma unroll
            for (int g2 = 0; g2 < 16; ++g2) s += sm.red[(g2 << 6) + t];
            ((float*)out)[blockIdx.x * 64 + t] = s;
        }
        return;
    }

    if (t < 64) {
        float s = 0.f;
        #pragma unroll
        for (int g2 = 0; g2 < 16; ++g2) s += sm.red[(g2 << 6) + t];
        sm.pooled[t] = s * (1.f / 8192.f);
    }
    __syncthreads();
    if (t < 128) {
        float acc = ldv<F32>(bc1, t);
        #pragma unroll 8
        for (int k = 0; k < 64; ++k) acc += sm.pooled[k] * ldv<F32>(Wc1, k * 128 + t);
        sm.hid[t] = fmaxf(acc, 0.f);
    }
    __syncthreads();
    if (t < 8) {
        float acc = ldv<F32>(bc2, t);
        #pragma unroll 8
        for (int k = 0; k < 128; ++k) acc += sm.hid[k] * ldv<F32>(Wc2, k * 8 + t);
        if constexpr (F32) ((float*)out)[t] = acc;
        else ((__hip_bfloat16*)out)[t] = __float2bfloat16(acc);
    }
}

// ================= fused single-dispatch kernel =================
#define SMEM_BYTES (86 * 1024)

// bf16 fast path: weights packed in LDS, overlays for phases B / finalize.
static __device__ void fused_bf16(unsigned char* smem, int& lastFlag,
    const void* ef, const void* We, const void* be, const void* M1w,
    const void* M1b, const void* M2w, const void* M2b, const void* W1,
    const void* W2, const void* Wc1, const void* bc1, const void* Wc2,
    const void* bc2, unsigned int* counter, float* partials, void* out)
{
    const int t = threadIdx.x, c = t & 63, w = t >> 6;
    const int base = blockIdx.x * 16;

    // ---- phase A pointers ----
    unsigned*       P1   = (unsigned*)smem;                 // [128][64] Wa|Wb
    unsigned short* Wh16 = (unsigned short*)(smem + 32768); // [128][64]
    unsigned short* W216 = (unsigned short*)(smem + 49152); // [64][64]
    float*          efs  = (float*)(smem + 57344);          // [32][128]
    float*          Hs   = (float*)(smem + 73728);          // [32][64]
    float*          ps    = (float*)(smem + 81920);         // [24][8][2]
    float*          dinvs = ps + 384;                       // [24][2]
    float*          facs  = dinvs + 48;                     // [24][2]

    // ---- stage weights (u32-wise, coalesced) ----
    {
        const unsigned* M1u = (const unsigned*)M1w;
        const unsigned* Weu = (const unsigned*)We;
        const unsigned* W2u = (const unsigned*)W2;
        const unsigned* efu = (const unsigned*)ef;
        #pragma unroll
        for (int rep = 0; rep < 4; ++rep) {
            const int j = rep * 1024 + t;                   // j < 4096
            const unsigned a = M1u[j];
            const unsigned b = M1u[4096 + j];
            const int k = j >> 5, c2 = (j & 31) * 2;
            P1[k * 64 + c2]     = (a & 0xFFFFu) | (b << 16);
            P1[k * 64 + c2 + 1] = (a >> 16) | (b & 0xFFFF0000u);
            ((unsigned*)Wh16)[j] = Weu[j];
        }
        #pragma unroll
        for (int rep = 0; rep < 2; ++rep)
            ((unsigned*)W216)[rep * 1024 + t] = W2u[rep * 1024 + t];
        #pragma unroll
        for (int rep = 0; rep < 2; ++rep) {
            const int j = rep * 1024 + t;                   // j < 2048
            const int row = j >> 6, cc = j & 63;
            const unsigned u = efu[(((base - 8 + row) & (NN - 1)) << 6) + cc];
            efs[row * 128 + cc * 2]     = blo(u);
            efs[row * 128 + cc * 2 + 1] = bhi(u);
        }
    }
    __syncthreads();

    // ---- GEMV stage 1: wave w owns ext nodes q0=w, q1=w+16 ----
    const int q0 = w, q1 = w + 16;
    float aA0 = 0.f, aA1 = 0.f, aB0 = 0.f, aB1 = 0.f;
    float aH0 = ldv<false>(be, c), aH1 = aH0;
    #pragma unroll 8
    for (int k = 0; k < 128; ++k) {
        const unsigned p = P1[k * 64 + c];
        const float wa = blo(p), wb = bhi(p);
        const float wh = b16f(Wh16[k * 64 + c]);
        const float e0 = efs[q0 * 128 + k], e1 = efs[q1 * 128 + k];
        aA0 = fmaf(e0, wa, aA0);  aA1 = fmaf(e1, wa, aA1);
        aB0 = fmaf(e0, wb, aB0);  aB1 = fmaf(e1, wb, aB1);
        aH0 = fmaf(e0, wh, aH0);  aH1 = fmaf(e1, wh, aH1);
    }
    __syncthreads();                       // all waves done reading P1

    // ---- overlay phase B over P1 region ----
    float* As = (float*)smem;              // [24][64] ext rows 4..27
    float* Bs = As + 24 * 64;              // [32][64]
    float* Gs = Bs + 32 * 64;              // [32][64]
    if (q0 >= 4 && q0 < 28) As[(q0 - 4) * 64 + c] = aA0;
    if (q1 >= 4 && q1 < 28) As[(q1 - 4) * 64 + c] = aA1;
    Bs[q0 * 64 + c] = aB0;  Bs[q1 * 64 + c] = aB1;
    Hs[q0 * 64 + c] = fmaxf(aH0, 0.f);
    Hs[q1 * 64 + c] = fmaxf(aH1, 0.f);
    __syncthreads();

    // ---- GEMV stage 2: G = relu(H) @ W2 ----
    {
        float g0 = 0.f, g1 = 0.f;
        #pragma unroll 8
        for (int k = 0; k < 64; ++k) {
            const float w2 = b16f(W216[k * 64 + c]);
            g0 = fmaf(Hs[q0 * 64 + k], w2, g0);
            g1 = fmaf(Hs[q1 * 64 + k], w2, g1);
        }
        Gs[q0 * 64 + c] = g0;  Gs[q1 * 64 + c] = g1;
    }
    __syncthreads();

    const float m1b_c = ldv<false>(M1b, c);
    const float m2w0  = ldv<false>(M2w, c * 2 + 0);
    const float m2w1  = ldv<false>(M2w, c * 2 + 1);
    const float m2b0  = ldv<false>(M2b, 0);
    const float m2b1  = ldv<false>(M2b, 1);
    const float cs0 = ldv<false>(W1, 0) + ldv<false>(W1, 2);
    const float cs1 = ldv<false>(W1, 1) + ldv<false>(W1, 3);

    // ---- phase 2: p(r,tt), r in [0,24) (node base-4+r = ext r+4) ----
    for (int pi = w; pi < 24 * 8; pi += 16) {
        const int r  = pi >> 3;
        const int tt = pi & 7;
        const int off = (tt < 4) ? (tt - 4) : (tt - 3);
        const float h = fmaxf(As[r * 64 + c] + Bs[(r + 4 + off) * 64 + c] + m1b_c, 0.f);
        float p0 = h * m2w0, p1 = h * m2w1;
        #pragma unroll
        for (int d2 = 32; d2; d2 >>= 1) {
            p0 += __shfl_xor(p0, d2);
            p1 += __shfl_xor(p1, d2);
        }
        if (c == 0) {
            ps[(r * 8 + tt) * 2 + 0] = p0 + m2b0;
            ps[(r * 8 + tt) * 2 + 1] = p1 + m2b1;
        }
    }
    __syncthreads();

    // ---- phase 3: s, dinv, fac ----
    if (t < 48) {
        const int r = t >> 1, aa = t & 1;
        float s = 0.f;
        #pragma unroll
        for (int tt = 0; tt < 8; ++tt) {
            const float p = ps[(r * 8 + tt) * 2 + aa];
            s += p * p;
        }
        const float dv = 1.f / sqrtf(fmaxf(s + 1e-5f, 1e-6f));
        dinvs[r * 2 + aa] = dv;
        facs[r * 2 + aa]  = 1.f - dv * dv * s;
    }
    __syncthreads();

    // ---- phase 4: Y rows + elu for the 16 owned nodes ----
    float accY = 0.f;
    #pragma unroll
    for (int it = 0; it < 2; ++it) {
        const int m = it * 8 + (t >> 7);   // owned node [0,16)
        const int a = (t >> 6) & 1;
        const int r = m + 4;               // p-local
        const int g = m + 8;               // ext index
        const float csa = a ? cs1 : cs0;
        const float di = dinvs[r * 2 + a];
        float v = facs[r * 2 + a] * Gs[g * 64 + c];
        #pragma unroll
        for (int tt = 0; tt < 8; ++tt) {
            const int off = (tt < 4) ? (tt - 4) : (tt - 3);
            v += di * ps[((r + off) * 8 + (7 - tt)) * 2 + a] * ps[(r * 8 + tt) * 2 + a]
                    * dinvs[(r + off) * 2 + a] * Gs[(g + off) * 64 + c];
        }
        const float x = csa * v;
        accY += (x > 0.f) ? x : expm1f(x);
    }

    // ---- block partial -> global ----
    float* red = (float*)(smem + 32768);   // over Wh16 (dead)
    red[t] = accY;
    __syncthreads();
    if (t < 64) {
        float s = 0.f;
        #pragma unroll
        for (int g2 = 0; g2 < 16; ++g2) s += red[(g2 << 6) + t];
        partials[blockIdx.x * 64 + t] = s;
    }
    __threadfence();
    __syncthreads();
    if (t == 0) {
        const unsigned old = atomicAdd(counter, 1u);
        lastFlag = (old == (unsigned)(gridDim.x - 1)) ? 1 : 0;
    }
    __syncthreads();
    if (!lastFlag) return;
    __threadfence();
    if (t == 0) *counter = 0;              // backup (memset also in-graph)

    // ---- finalize overlays (As/Bs/Gs dead) ----
    float* Wc1s = (float*)smem;            // [64][128] 32KB
    float* Wc2s = (float*)(smem + 36864);  // [128][8] 4KB (red keeps 32768..36864)
    float* pooled = (float*)(smem + 40960);
    float* hid = pooled + 64;
    {
        const unsigned* Wc1u = (const unsigned*)Wc1;
        const unsigned* Wc2u = (const unsigned*)Wc2;
        #pragma unroll
        for (int rep = 0; rep < 4; ++rep) {
            const int j = rep * 1024 + t;                   // j < 4096
            const unsigned u = Wc1u[j];
            const int k = j >> 6, c2 = (j & 63) * 2;
            Wc1s[k * 128 + c2]     = blo(u);
            Wc1s[k * 128 + c2 + 1] = bhi(u);
        }
        if (t < 512) {
            const unsigned u = Wc2u[t];
            const int k = t >> 2, c2 = (t & 3) * 2;
            Wc2s[k * 8 + c2]     = blo(u);
            Wc2s[k * 8 + c2 + 1] = bhi(u);
        }
    }
    // fixed-order reduce of 256 partial vectors
    {
        float s = 0.f;
        for (int b = w; b < NBLKF; b += 16) s += partials[b * 64 + c];
        red[w * 64 + c] = s;
    }
    __syncthreads();
    if (t < 64) {
        float tot = 0.f;
        #pragma unroll
        for (int g2 = 0; g2 < 16; ++g2) tot += red[g2 * 64 + t];
        pooled[t] = tot * (1.0f / 8192.0f);
    }
    __syncthreads();
    if (t < 128) {
        float acc = ldv<false>(bc1, t);
        #pragma unroll 8
        for (int k = 0; k < 64; ++k) acc = fmaf(pooled[k], Wc1s[k * 128 + t], acc);
        hid[t] = fmaxf(acc, 0.f);
    }
    __syncthreads();
    if (t < 8) {
        float acc = ldv<false>(bc2, t);
        #pragma unroll 8
        for (int k = 0; k < 128; ++k) acc = fmaf(hid[k], Wc2s[k * 8 + t], acc);
        ((__hip_bfloat16*)out)[t] = __float2bfloat16(acc);
    }
}

// f32 path (never triggers in practice): R21-proven global-load fused body.
static __device__ void fused_f32(unsigned char* smem, int& lastFlag,
    const void* ef, const void* We, const void* be, const void* M1w,
    const void* M1b, const void* M2w, const void* M2b, const void* W1,
    const void* W2, const void* Wc1, const void* bc1, const void* Wc2,
    const void* bc2, unsigned int* counter, float* partials, void* out)
{
    const int t = threadIdx.x, c = t & 63, w = t >> 6;
    const int base = blockIdx.x * 16;
    float* efs = (float*)smem;                 // [32][128]
    float* Hs  = (float*)(smem + 16384);       // [32][64]
    float* As  = (float*)(smem + 24576);       // [24][64]
    float* Bs  = (float*)(smem + 30720);       // [32][64]
    float* Gs  = (float*)(smem + 38912);       // [32][64]
    float* ps  = (float*)(smem + 47104);       // [24][8][2]
    float* dinvs = ps + 384;
    float* facs  = dinvs + 48;
    float* red = (float*)(smem + 49152);       // [1024]
    float* pooled = (float*)(smem + 53248);
    float* hid = pooled + 64;

    for (int idx = t; idx < 32 * 128; idx += 1024) {
        const int row = idx >> 7, k = idx & 127;
        efs[idx] = ((const float*)ef)[(((base - 8 + row) & (NN - 1)) << 7) + k];
    }
    __syncthreads();
    const int q0 = w, q1 = w + 16;
    {
        float aA0 = 0.f, aA1 = 0.f, aB0 = 0.f, aB1 = 0.f;
        float aH0 = ((const float*)be)[c], aH1 = aH0;
        #pragma unroll 4
        for (int k = 0; k < 128; ++k) {
            const float wa  = ((const float*)M1w)[k * 64 + c];
            const float wb  = ((const float*)M1w)[8192 + k * 64 + c];
            const float wh  = ((const float*)We)[k * 64 + c];
            const float e0 = efs[q0 * 128 + k], e1 = efs[q1 * 128 + k];
            aA0 = fmaf(e0, wa, aA0);  aA1 = fmaf(e1, wa, aA1);
            aB0 = fmaf(e0, wb, aB0);  aB1 = fmaf(e1, wb, aB1);
            aH0 = fmaf(e0, wh, aH0);  aH1 = fmaf(e1, wh, aH1);
        }
        if (q0 >= 4 && q0 < 28) As[(q0 - 4) * 64 + c] = aA0;
        if (q1 >= 4 && q1 < 28) As[(q1 - 4) * 64 + c] = aA1;
        Bs[q0 * 64 + c] = aB0;  Bs[q1 * 64 + c] = aB1;
        Hs[q0 * 64 + c] = fmaxf(aH0, 0.f);
        Hs[q1 * 64 + c] = fmaxf(aH1, 0.f);
    }
    __syncthreads();
    {
        float g0 = 0.f, g1 = 0.f;
        #pragma unroll 4
        for (int k = 0; k < 64; ++k) {
            const float w2 = ((const float*)W2)[k * 64 + c];
            g0 = fmaf(Hs[q0 * 64 + k], w2, g0);
            g1 = fmaf(Hs[q1 * 64 + k], w2, g1);
        }
        Gs[q0 * 64 + c] = g0;  Gs[q1 * 64 + c] = g1;
    }
    __syncthreads();

    const float m1b_c = ((const float*)M1b)[c];
    const float m2w0  = ((const float*)M2w)[c * 2 + 0];
    const float m2w1  = ((const float*)M2w)[c * 2 + 1];
    const float m2b0  = ((const float*)M2b)[0];
    const float m2b1  = ((const float*)M2b)[1];
    const float cs0 = ((const float*)W1)[0] + ((const float*)W1)[2];
    const float cs1 = ((const float*)W1)[1] + ((const float*)W1)[3];

    for (int pi = w; pi < 24 * 8; pi += 16) {
        const int r  = pi >> 3;
        const int tt = pi & 7;
        const int off = (tt < 4) ? (tt - 4) : (tt - 3);
        const float h = fmaxf(As[r * 64 + c] + Bs[(r + 4 + off) * 64 + c] + m1b_c, 0.f);
        float p0 = h * m2w0, p1 = h * m2w1;
        #pragma unroll
        for (int d2 = 32; d2; d2 >>= 1) {
            p0 += __shfl_xor(p0, d2);
            p1 += __shfl_xor(p1, d2);
        }
        if (c == 0) {
            ps[(r * 8 + tt) * 2 + 0] = p0 + m2b0;
            ps[(r * 8 + tt) * 2 + 1] = p1 + m2b1;
        }
    }
    __syncthreads();
    if (t < 48) {
        const int r = t >> 1, aa = t & 1;
        float s = 0.f;
        #pragma unroll
        for (int tt = 0; tt < 8; ++tt) {
            const float p = ps[(r * 8 + tt) * 2 + aa];
            s += p * p;
        }
        const float dv = 1.f / sqrtf(fmaxf(s + 1e-5f, 1e-6f));
        dinvs[r * 2 + aa] = dv;
        facs[r * 2 + aa]  = 1.f - dv * dv * s;
    }
    __syncthreads();
    float accY = 0.f;
    #pragma unroll
    for (int it = 0; it < 2; ++it) {
        const int m = it * 8 + (t >> 7);
        const int a = (t >> 6) & 1;
        const int r = m + 4;
        const int g = m + 8;
        const float csa = a ? cs1 : cs0;
        const float di = dinvs[r * 2 + a];
        float v = facs[r * 2 + a] * Gs[g * 64 + c];
        #pragma unroll
        for (int tt = 0; tt < 8; ++tt) {
            const int off = (tt < 4) ? (tt - 4) : (tt - 3);
            v += di * ps[((r + off) * 8 + (7 - tt)) * 2 + a] * ps[(r * 8 + tt) * 2 + a]
                    * dinvs[(r + off) * 2 + a] * Gs[(g + off) * 64 + c];
        }
        const float x = csa * v;
        accY += (x > 0.f) ? x : expm1f(x);
    }
    red[t] = accY;
    __syncthreads();
    if (t < 64) {
        float s = 0.f;
        #pragma unroll
        for (int g2 = 0; g2 < 16; ++g2) s += red[(g2 << 6) + t];
        partials[blockIdx.x * 64 + t] = s;
    }
    __threadfence();
    __syncthreads();
    if (t == 0) {
        const unsigned old = atomicAdd(counter, 1u);
        lastFlag = (old == (unsigned)(gridDim.x - 1)) ? 1 : 0;
    }
    __syncthreads();
    if (!lastFlag) return;
    __threadfence();
    if (t == 0) *counter = 0;

    {
        float s = 0.f;
        for (int b = w; b < NBLKF; b += 16) s += partials[b * 64 + c];
        red[w * 64 + c] = s;
    }
    __syncthreads();
    if (t < 64) {
        float tot = 0.f;
        #pragma unroll
        for (int g2 = 0; g2 < 16; ++g2) tot += red[g2 * 64 + t];
        pooled[t] = tot * (1.0f / 8192.0f);
    }
    __syncthreads();
    if (t < 128) {
        float acc = ((const float*)bc1)[t];
        #pragma unroll 8
        for (int k = 0; k < 64; ++k) acc += pooled[k] * ((const float*)Wc1)[k * 128 + t];
        hid[t] = fmaxf(acc, 0.f);
    }
    __syncthreads();
    if (t < 8) {
        float acc = ((const float*)bc2)[t];
        #pragma unroll 8
        for (int k = 0; k < 128; ++k) acc += hid[k] * ((const float*)Wc2)[k * 8 + t];
        ((float*)out)[t] = acc;
    }
}

__global__ __launch_bounds__(1024) void sheaf_fused(
    const void* ef, const void* We, const void* be, const void* M1w,
    const void* M1b, const void* M2w, const void* M2b, const void* W1,
    const void* W2, const void* Wc1, const void* bc1, const void* Wc2,
    const void* bc2, unsigned int* counter, float* partials, void* out)
{
    __shared__ __align__(16) unsigned char smem[SMEM_BYTES];
    __shared__ int flag;
    __shared__ int lastFlag;
    const int t = threadIdx.x;
    if (t == 0) flag = 0;
    __syncthreads();
    {
        const __hip_bfloat16* efh = (const __hip_bfloat16*)ef;
        bool big = false;
        #pragma unroll
        for (int k = 0; k < 8; ++k) {
            const float v = __bfloat162float(efh[t * 8 + k]);
            big |= !(fabsf(v) < 1e4f);
        }
        if (big) atomicOr(&flag, 1);
    }
    __syncthreads();
    if (flag)
        fused_f32(smem, lastFlag, ef, We, be, M1w, M1b, M2w, M2b, W1, W2,
                  Wc1, bc1, Wc2, bc2, counter, partials, out);
    else
        fused_bf16(smem, lastFlag, ef, We, be, M1w, M1b, M2w, M2b, W1, W2,
                   Wc1, bc1, Wc2, bc2, counter, partials, out);
}

// Finalize (R17 fallback path)
__global__ __launch_bounds__(256) void sheaf_finalize(
    const void* ef, const void* Wc1, const void* bc1, const void* Wc2,
    const void* bc2, const float* partials, int nparts, void* out)
{
    __shared__ SmemFin sm;
    __shared__ int flag;
    const int t = threadIdx.x;
    if (t == 0) flag = 0;
    __syncthreads();
    {
        const __hip_bfloat16* efh = (const __hip_bfloat16*)ef;
        bool big = false;
        #pragma unroll
        for (int k = 0; k < 8; ++k) {
            const float v = __bfloat162float(efh[t * 8 + k]);
            big |= !(fabsf(v) < 1e4f);
        }
        if (big) atomicOr(&flag, 1);
    }
    __syncthreads();
    const bool f32 = (flag != 0);

    if (f32) {
        for (int idx = t; idx < 64 * 128; idx += 256)
            sm.Wc1s[idx >> 7][idx & 127] = ((const float*)Wc1)[idx];
        for (int idx = t; idx < 128 * 8; idx += 256)
            sm.Wc2s[idx >> 3][idx & 7] = ((const float*)Wc2)[idx];
    } else {
        for (int j = t; j < 4096; j += 256) {
            const int k = j >> 6, c2 = (j & 63) * 2;
            const unsigned u = ((const unsigned*)Wc1)[j];
            sm.Wc1s[k][c2] = blo(u);  sm.Wc1s[k][c2 + 1] = bhi(u);
        }
        for (int j = t; j < 512; j += 256) {
            const int k = j >> 2, c2 = (j & 3) * 2;
            const unsigned u = ((const unsigned*)Wc2)[j];
            sm.Wc2s[k][c2] = blo(u);  sm.Wc2s[k][c2 + 1] = bhi(u);
        }
    }

    const int h = t & 63, g = t >> 6;
    float s = 0.f;
    for (int b = g; b < nparts; b += 4) s += partials[b * 64 + h];
    sm.red[t] = s;
    __syncthreads();
    if (t < 64)
        sm.pooled[t] = (sm.red[t] + sm.red[t + 64] + sm.red[t + 128] + sm.red[t + 192])
                       * (1.f / 8192.f);
    __syncthreads();
    if (t < 128) {
        float acc = ldr(bc1, t, f32);
        #pragma unroll 8
        for (int k = 0; k < 64; ++k) acc = fmaf(sm.pooled[k], sm.Wc1s[k][t], acc);
        sm.hid[t] = fmaxf(acc, 0.f);
    }
    __syncthreads();
    if (t < 8) {
        float acc = ldr(bc2, t, f32);
        #pragma unroll 8
        for (int k = 0; k < 128; ++k) acc = fmaf(sm.hid[k], sm.Wc2s[k][t], acc);
        if (f32) ((float*)out)[t] = acc;
        else ((__hip_bfloat16*)out)[t] = __float2bfloat16(acc);
    }
}

__global__ __launch_bounds__(1024) void SheafConvolutionalNetwork_81698867905240_kernel(
    const void* ef, const void* We, const void* be, const void* M1w,
    const void* M1b, const void* M2w, const void* M2b, const void* W1,
    const void* W2, const void* Wc1, const void* bc1, const void* Wc2,
    const void* bc2, void* out)
{
    __shared__ Smem sm;
    __shared__ int flag;
    const int t = threadIdx.x;
    if (t == 0) flag = 0;
    __syncthreads();
    {
        const __hip_bfloat16* efh = (const __hip_bfloat16*)ef;
        bool big = false;
        #pragma unroll
        for (int k = 0; k < 8; ++k) {
            const float v = __bfloat162float(efh[t * 8 + k]);
            big |= !(fabsf(v) < 1e4f);
        }
        if (big) atomicOr(&flag, 1);
    }
    __syncthreads();
    if (flag)
        body<true >(sm, ef, We, be, M1w, M1b, M2w, M2b, W1, W2, Wc1, bc1, Wc2, bc2, out);
    else
        body<false>(sm, ef, We, be, M1w, M1b, M2w, M2b, W1, W2, Wc1, bc1, Wc2, bc2, out);
}

extern "C" void kernel_launch(void* const* d_in, const int* in_sizes, int n_in,
                              void* d_out, int out_size, void* d_ws, size_t ws_size,
                              hipStream_t stream)
{
    (void)in_sizes; (void)n_in; (void)out_size;
    (void)hipGetLastError();   // clear stale error

    if (d_ws != nullptr && ws_size >= (size_t)WS_FUSED) {
        unsigned int* counter = (unsigned int*)d_ws;
        float* partials = (float*)((char*)d_ws + 4096);
        (void)hipMemsetAsync(d_ws, 0, 4096, stream);   // in-graph counter reset
        sheaf_fused<<<dim3(NBLKF), dim3(1024), 0, stream>>>(
            d_in[0], d_in[1], d_in[2], d_in[3], d_in[4], d_in[5], d_in[6],
            d_in[7], d_in[8], d_in[9], d_in[10], d_in[11], d_in[12],
            counter, partials, d_out);
    } else if (d_ws != nullptr && ws_size >= (size_t)WS_R17) {
        SheafConvolutionalNetwork_81698867905240_kernel<<<dim3(NGRID), dim3(1024), 0, stream>>>(
            d_in[0], d_in[1], d_in[2], d_in[3], d_in[4], d_in[5], d_in[6],
            d_in[7], d_in[8], d_in[9], d_in[10], d_in[11], d_in[12], d_ws);
        sheaf_finalize<<<dim3(1), dim3(256), 0, stream>>>(
            d_in[0], d_in[9], d_in[10], d_in[11], d_in[12],
            (const float*)d_ws, NGRID, d_out);
    } else {
        SheafConvolutionalNetwork_81698867905240_kernel<<<dim3(1), dim3(1024), 0, stream>>>(
            d_in[0], d_in[1], d_in[2], d_in[3], d_in[4], d_in[5], d_in[6],
            d_in[7], d_in[8], d_in[9], d_in[10], d_in[11], d_in[12], d_out);
    }

    if (hipGetLastError() != hipSuccess)
        (void)hipMemsetAsync(d_out, 0x41, 16, stream);
}